// Round 2
// baseline (117.793 us; speedup 1.0000x reference)
//
#include <hip/hip_runtime.h>
#include <cmath>

typedef unsigned short u16;
typedef __attribute__((ext_vector_type(8))) short s8v;   // 8 bf16 payload (4 VGPRs)
typedef __attribute__((ext_vector_type(4))) float f4v;   // MFMA accumulator

__device__ __forceinline__ u16 f2bf(float f) {
    union { float f; unsigned u; } v; v.f = f;
    unsigned r = v.u + 0x7FFFu + ((v.u >> 16) & 1u);   // RNE
    return (u16)(r >> 16);
}
__device__ __forceinline__ float bf2f(u16 h) {
    union { unsigned u; float f; } v; v.u = ((unsigned)h) << 16;
    return v.f;
}

// ---------------------------------------------------------------------------
// prep: W2T[n][k] = bf16(W2[k][n]);  VT[q][p] = bf16(W2[p][q] * U[q][p]),
//       U[q][p] = sum_i W3[q][i] * W1[i][p].   Also zero trJ.
// grid (32,32), 256 threads; 32x32 tiles.
// ---------------------------------------------------------------------------
__launch_bounds__(256)
__global__ void cnf_prep(const float* __restrict__ W1, const float* __restrict__ W2,
                         const float* __restrict__ W3,
                         u16* __restrict__ W2T, u16* __restrict__ VT,
                         float* __restrict__ trJ)
{
    __shared__ float w2s[32][33];
    const int a = blockIdx.x * 32;   // k / p base (rows of W2)
    const int b = blockIdx.y * 32;   // n / q base (cols of W2)
    const int t = threadIdx.x;
    #pragma unroll
    for (int it = 0; it < 4; ++it) {
        int idx = t + it * 256;
        int r = idx >> 5, c = idx & 31;
        w2s[r][c] = W2[(a + r) * 1024 + (b + c)];
    }
    __syncthreads();
    #pragma unroll
    for (int it = 0; it < 4; ++it) {
        int idx = t + it * 256;
        int rr = idx >> 5, cc = idx & 31;
        W2T[(b + rr) * 1024 + (a + cc)] = f2bf(w2s[cc][rr]);
    }
    #pragma unroll
    for (int it = 0; it < 4; ++it) {
        int idx = t + it * 256;
        int qq = idx >> 5, pp = idx & 31;
        float u = 0.f;
        const float* w3row = W3 + (b + qq) * 64;
        const float* w1col = W1 + (a + pp);
        #pragma unroll 8
        for (int i = 0; i < 64; ++i) u += w3row[i] * w1col[i * 1024];
        VT[(b + qq) * 1024 + (a + pp)] = f2bf(w2s[pp][qq] * u);
    }
    if (blockIdx.y == 0 && t < 128) trJ[blockIdx.x * 128 + t] = 0.f;
}

// ---------------------------------------------------------------------------
// gemm1: h1 = tanh(x_in @ W1 + b1), g1 = 1 - h1^2   (K=64, fp32 vector ALU)
// grid 2048, 256 threads. Block: 8 rows x 256 cols.
// ---------------------------------------------------------------------------
__launch_bounds__(256)
__global__ void cnf_gemm1(const float* __restrict__ x, const float* __restrict__ W1,
                          const float* __restrict__ b1,
                          u16* __restrict__ h1, u16* __restrict__ g1)
{
    __shared__ float xs[8][64];
    const int t = threadIdx.x;
    const int b0 = (blockIdx.x >> 2) * 8;
    const int jt = blockIdx.x & 3;
    #pragma unroll
    for (int it = 0; it < 2; ++it) {
        int idx = t + it * 256;
        int row = idx >> 6, i = idx & 63;
        xs[row][i] = x[(b0 + row) * 65 + 1 + i];
    }
    __syncthreads();
    const int j = jt * 256 + t;
    float acc[8] = {0.f,0.f,0.f,0.f,0.f,0.f,0.f,0.f};
    #pragma unroll 8
    for (int i = 0; i < 64; ++i) {
        float w = W1[i * 1024 + j];
        #pragma unroll
        for (int r = 0; r < 8; ++r) acc[r] += xs[r][i] * w;
    }
    const float bv = b1[j];
    #pragma unroll
    for (int r = 0; r < 8; ++r) {
        float h = tanhf(acc[r] + bv);
        float gg = 1.f - h * h;
        h1[(b0 + r) * 1024 + j] = f2bf(h);
        g1[(b0 + r) * 1024 + j] = f2bf(gg);
    }
}

// ---------------------------------------------------------------------------
// mid: fused dual GEMM over K=1024:
//   C2 = h1 @ W2   -> h2 = tanh(C2+b2) (stored bf16), g2 = 1-h2^2 (in reg)
//   T  = g1 @ V    -> trJ[row] += sum_col T*g2   (shfl reduce + atomicAdd)
// Tile 128x64, BK=32, 4 waves (2x2), each wave 64x32 (4x2 16x16 frags).
// B operands are n-major (W2T, VT) so fragments are contiguous 16B reads.
// ---------------------------------------------------------------------------
__launch_bounds__(256)
__global__ void cnf_mid(const u16* __restrict__ h1, const u16* __restrict__ g1,
                        const u16* __restrict__ W2T, const u16* __restrict__ VT,
                        const float* __restrict__ b2,
                        u16* __restrict__ h2, float* __restrict__ trJ)
{
    __shared__ __align__(16) u16 As1[128][40];
    __shared__ __align__(16) u16 As2[128][40];
    __shared__ __align__(16) u16 Bs1[64][40];
    __shared__ __align__(16) u16 Bs2[64][40];

    const int t = threadIdx.x;
    const int wave = t >> 6, lane = t & 63;
    const int wm = wave >> 1, wn = wave & 1;
    const int g = lane >> 4, lr = lane & 15;
    const int arow0 = blockIdx.x * 128;
    const int bcol0 = blockIdx.y * 64;

    f4v acc1[4][2], acc2[4][2];
    #pragma unroll
    for (int mi = 0; mi < 4; ++mi)
        #pragma unroll
        for (int ni = 0; ni < 2; ++ni) {
            acc1[mi][ni] = f4v{0.f, 0.f, 0.f, 0.f};
            acc2[mi][ni] = f4v{0.f, 0.f, 0.f, 0.f};
        }

    const int srow = t >> 2, sch = (t & 3) * 8;
    for (int k0 = 0; k0 < 1024; k0 += 32) {
        *(s8v*)&As1[srow][sch]      = *(const s8v*)&h1[(arow0 + srow) * 1024      + k0 + sch];
        *(s8v*)&As1[srow + 64][sch] = *(const s8v*)&h1[(arow0 + srow + 64) * 1024 + k0 + sch];
        *(s8v*)&As2[srow][sch]      = *(const s8v*)&g1[(arow0 + srow) * 1024      + k0 + sch];
        *(s8v*)&As2[srow + 64][sch] = *(const s8v*)&g1[(arow0 + srow + 64) * 1024 + k0 + sch];
        *(s8v*)&Bs1[srow][sch]      = *(const s8v*)&W2T[(bcol0 + srow) * 1024     + k0 + sch];
        *(s8v*)&Bs2[srow][sch]      = *(const s8v*)&VT[(bcol0 + srow) * 1024      + k0 + sch];
        __syncthreads();

        s8v af1[4], af2[4], bf1[2], bf2[2];
        #pragma unroll
        for (int mi = 0; mi < 4; ++mi) {
            af1[mi] = *(const s8v*)&As1[wm * 64 + mi * 16 + lr][g * 8];
            af2[mi] = *(const s8v*)&As2[wm * 64 + mi * 16 + lr][g * 8];
        }
        #pragma unroll
        for (int ni = 0; ni < 2; ++ni) {
            bf1[ni] = *(const s8v*)&Bs1[wn * 32 + ni * 16 + lr][g * 8];
            bf2[ni] = *(const s8v*)&Bs2[wn * 32 + ni * 16 + lr][g * 8];
        }
        #pragma unroll
        for (int mi = 0; mi < 4; ++mi)
            #pragma unroll
            for (int ni = 0; ni < 2; ++ni) {
                acc1[mi][ni] = __builtin_amdgcn_mfma_f32_16x16x32_bf16(af1[mi], bf1[ni], acc1[mi][ni], 0, 0, 0);
                acc2[mi][ni] = __builtin_amdgcn_mfma_f32_16x16x32_bf16(af2[mi], bf2[ni], acc2[mi][ni], 0, 0, 0);
            }
        __syncthreads();
    }

    // epilogue: h2/g2 + trace partial reduction
    #pragma unroll
    for (int mi = 0; mi < 4; ++mi) {
        const int rowb = arow0 + wm * 64 + mi * 16 + g * 4;
        float vs[4] = {0.f, 0.f, 0.f, 0.f};
        #pragma unroll
        for (int ni = 0; ni < 2; ++ni) {
            const int col = bcol0 + wn * 32 + ni * 16 + lr;
            const float bv = b2[col];
            #pragma unroll
            for (int r = 0; r < 4; ++r) {
                float a2 = acc1[mi][ni][r] + bv;
                float hh = tanhf(a2);
                float gg = 1.f - hh * hh;
                h2[(rowb + r) * 1024 + col] = f2bf(hh);
                vs[r] += acc2[mi][ni][r] * gg;
            }
        }
        #pragma unroll
        for (int off = 1; off < 16; off <<= 1)
            #pragma unroll
            for (int r = 0; r < 4; ++r)
                vs[r] += __shfl_xor(vs[r], off);
        if (lr == 0) {
            #pragma unroll
            for (int r = 0; r < 4; ++r)
                atomicAdd(&trJ[rowb + r], vs[r]);
        }
    }
}

// ---------------------------------------------------------------------------
// out: y = h2 @ W3 + b3 -> out[:,1:65];  out[:,0] = -trJ
// grid 512, 256 threads. Block: 8 rows; 64 cols x 4 K-slices per thread.
// ---------------------------------------------------------------------------
__launch_bounds__(256)
__global__ void cnf_out(const u16* __restrict__ h2, const float* __restrict__ W3,
                        const float* __restrict__ b3, const float* __restrict__ trJ,
                        float* __restrict__ out)
{
    __shared__ __align__(16) u16 hs[8][1024];
    __shared__ float red[4][8][64];
    const int t = threadIdx.x;
    const int b0 = blockIdx.x * 8;
    #pragma unroll
    for (int it = 0; it < 4; ++it) {          // FIX: 4 iters -> all 8 rows staged
        int idx = t + it * 256;
        int row = idx >> 7, ch = idx & 127;
        *(s8v*)&hs[row][ch * 8] = *(const s8v*)&h2[(b0 + row) * 1024 + ch * 8];
    }
    __syncthreads();
    const int c = t & 63, s = t >> 6;
    float acc[8] = {0.f,0.f,0.f,0.f,0.f,0.f,0.f,0.f};
    for (int k = s * 256; k < s * 256 + 256; ++k) {
        float w = W3[k * 64 + c];
        #pragma unroll
        for (int r = 0; r < 8; ++r) acc[r] += bf2f(hs[r][k]) * w;
    }
    #pragma unroll
    for (int r = 0; r < 8; ++r) red[s][r][c] = acc[r];
    __syncthreads();
    for (int o = t; o < 512; o += 256) {
        int r = o >> 6, cc = o & 63;
        float sum = red[0][r][cc] + red[1][r][cc] + red[2][r][cc] + red[3][r][cc] + b3[cc];
        out[(b0 + r) * 65 + 1 + cc] = sum;
    }
    if (t < 8) out[(b0 + t) * 65] = -trJ[b0 + t];
}

// ---------------------------------------------------------------------------
extern "C" void kernel_launch(void* const* d_in, const int* in_sizes, int n_in,
                              void* d_out, int out_size, void* d_ws, size_t ws_size,
                              hipStream_t stream) {
    const float* x  = (const float*)d_in[0];
    const float* W1 = (const float*)d_in[1];
    const float* b1 = (const float*)d_in[2];
    const float* W2 = (const float*)d_in[3];
    const float* b2 = (const float*)d_in[4];
    const float* W3 = (const float*)d_in[5];
    const float* b3 = (const float*)d_in[6];
    float* out = (float*)d_out;

    char* ws = (char*)d_ws;
    u16*   h1b = (u16*)(ws);                       //  8 MB  (4096x1024 bf16)
    u16*   g1b = (u16*)(ws + (size_t)( 8u << 20)); //  8 MB
    u16*   h2b = (u16*)(ws + (size_t)(16u << 20)); //  8 MB
    u16*   W2T = (u16*)(ws + (size_t)(24u << 20)); //  2 MB  (1024x1024 bf16, n-major)
    u16*   VTb = (u16*)(ws + (size_t)(26u << 20)); //  2 MB
    float* trJ = (float*)(ws + (size_t)(28u << 20)); // 16 KB

    cnf_prep <<<dim3(32, 32), 256, 0, stream>>>(W1, W2, W3, W2T, VTb, trJ);
    cnf_gemm1<<<2048,         256, 0, stream>>>(x, W1, b1, h1b, g1b);
    cnf_mid  <<<dim3(32, 16), 256, 0, stream>>>(h1b, g1b, W2T, VTb, b2, h2b, trJ);
    cnf_out  <<<512,          256, 0, stream>>>(h2b, W3, b3, trJ, out);
}